// Round 1
// baseline (323.719 us; speedup 1.0000x reference)
//
#include <hip/hip_runtime.h>
#include <math.h>

#define ACC_BITS 23

// Bit-exact replica of the reference's integer_multiply_shift_round.
// nm/e are wave-uniform (derived from scalar inputs), so the branch is uniform.
__device__ __forceinline__ long long fixed_point_mul(long long xi, long long nm, int e) {
    long long tmp = xi * nm;
    if (e - ACC_BITS >= 0) {
        return tmp << (e - ACC_BITS);
    } else {
        int sr = ACC_BITS - e;                               // sr >= 1 here
        long long nudge = (1LL << (sr - 1)) - (long long)(tmp < 0);
        return (tmp + nudge) >> sr;                          // arithmetic shift, matches jnp int64 >>
    }
}

__global__ void __launch_bounds__(256)
quantact_kernel(const float4* __restrict__ x,
                const float4* __restrict__ idn,
                const float* __restrict__ pre_sf,
                const float* __restrict__ id_sf,
                const float* __restrict__ xminp,
                const float* __restrict__ xmaxp,
                float4* __restrict__ out,
                float* __restrict__ out_scale,
                int n4, int n)
{
    // ---- wave-uniform scalar setup (amortized over ~32 elements/thread) ----
    float s = fmaxf(fabsf(xminp[0]), fabsf(xmaxp[0]));
    s = fmaxf(s, 1e-8f);               // jnp.clip(v, 1e-8, None)
    float scale = s / 127.0f;          // fp32 division, bit-exact vs reference

    double s64  = (double)scale;
    double ns_x = (double)pre_sf[0] / s64;
    double ns_i = (double)id_sf[0] / s64;

    int e_x, e_i;
    double m_x = frexp(ns_x, &e_x);    // m in [0.5, 1)
    double m_i = frexp(ns_i, &e_i);
    // jnp.round = round-half-to-even = rint under default FE mode
    long long nm_x = (long long)rint(m_x * 8388608.0);   // 2^23
    long long nm_i = (long long)rint(m_i * 8388608.0);

    int tid    = blockIdx.x * blockDim.x + threadIdx.x;
    int stride = gridDim.x * blockDim.x;
    if (tid == 0) *out_scale = scale;  // second tuple output

    for (int i = tid; i < n4; i += stride) {
        float4 xv = x[i];
        float4 iv = idn[i];
        float4 ov;

        {
            long long o = fixed_point_mul((long long)xv.x, nm_x, e_x)
                        + fixed_point_mul((long long)iv.x, nm_i, e_i);
            o = o < -128 ? -128 : (o > 127 ? 127 : o);
            ov.x = (float)(int)o * scale;
        }
        {
            long long o = fixed_point_mul((long long)xv.y, nm_x, e_x)
                        + fixed_point_mul((long long)iv.y, nm_i, e_i);
            o = o < -128 ? -128 : (o > 127 ? 127 : o);
            ov.y = (float)(int)o * scale;
        }
        {
            long long o = fixed_point_mul((long long)xv.z, nm_x, e_x)
                        + fixed_point_mul((long long)iv.z, nm_i, e_i);
            o = o < -128 ? -128 : (o > 127 ? 127 : o);
            ov.z = (float)(int)o * scale;
        }
        {
            long long o = fixed_point_mul((long long)xv.w, nm_x, e_x)
                        + fixed_point_mul((long long)iv.w, nm_i, e_i);
            o = o < -128 ? -128 : (o > 127 ? 127 : o);
            ov.w = (float)(int)o * scale;
        }

        out[i] = ov;
    }

    // tail for n % 4 != 0 (not hit for this shape, kept for generality)
    const float* xs  = (const float*)x;
    const float* is_ = (const float*)idn;
    float* os = (float*)out;
    for (int j = n4 * 4 + tid; j < n; j += stride) {
        long long o = fixed_point_mul((long long)xs[j], nm_x, e_x)
                    + fixed_point_mul((long long)is_[j], nm_i, e_i);
        o = o < -128 ? -128 : (o > 127 ? 127 : o);
        os[j] = (float)(int)o * scale;
    }
}

extern "C" void kernel_launch(void* const* d_in, const int* in_sizes, int n_in,
                              void* d_out, int out_size, void* d_ws, size_t ws_size,
                              hipStream_t stream) {
    const float4* x      = (const float4*)d_in[0];
    const float4* idn    = (const float4*)d_in[1];
    const float*  pre_sf = (const float*)d_in[2];
    const float*  id_sf  = (const float*)d_in[3];
    const float*  xmin   = (const float*)d_in[4];
    const float*  xmax   = (const float*)d_in[5];

    int n  = in_sizes[0];          // 4*4096*2048 = 33,554,432
    int n4 = n / 4;

    float* out       = (float*)d_out;
    float* out_scale = out + n;    // tuple output 1, concatenated flat

    const int block = 256;
    int grid = 4096;               // grid-stride: ~8 float4 iters/thread, amortizes fp64 setup
    int max_grid = (n4 + block - 1) / block;
    if (grid > max_grid) grid = max_grid;
    if (grid < 1) grid = 1;

    quantact_kernel<<<grid, block, 0, stream>>>(x, idn, pre_sf, id_sf, xmin, xmax,
                                                (float4*)out, out_scale, n4, n);
}